// Round 1
// baseline (165.134 us; speedup 1.0000x reference)
//
#include <hip/hip_runtime.h>
#include <math.h>

#define B 4
#define HW 76800       // 240*320
#define NBINS 256
#define NC 257         // bins + pad center
#define K1_BLOCKS 300
#define K2_BPB 50      // blocks per batch (50*256*6 == 76800 exactly)
#define P 6            // pixels per thread
#define TPB 256

// ws layout (4-byte words):
//   [0, 600)                : K1 per-block {maxT, maxC} pairs
//   [600, 600+200*257)      : K2 per-(b,block) per-m dir1 min partials
//   [52000, 52200)          : K2 per-(b,block) dir2 sum partials
#define WS_MAX_OFF  0
#define WS_MIN_OFF  600
#define WS_DIR2_OFF (600 + B*K2_BPB*NC)   // 52000

__global__ __launch_bounds__(256) void kmax(const float* __restrict__ target,
                                            const int* __restrict__ mask,
                                            const float* __restrict__ centers,
                                            float* __restrict__ ws_max) {
    int tid = blockIdx.x * 256 + threadIdx.x;
    const int stride = K1_BLOCKS * 256;   // 76800
    float mT = -INFINITY;
#pragma unroll
    for (int r = 0; r < 4; ++r) {         // 4*76800 = 307200 = B*HW exactly
        int i = tid + r * stride;
        float v = target[i];
        if (mask[i]) mT = fmaxf(mT, v);
    }
    float mC = -INFINITY;
    if (tid < B * NBINS) mC = centers[tid];
    for (int o = 32; o > 0; o >>= 1) {
        mT = fmaxf(mT, __shfl_down(mT, o));
        mC = fmaxf(mC, __shfl_down(mC, o));
    }
    __shared__ float sT[4], sC[4];
    int w = threadIdx.x >> 6;
    if ((threadIdx.x & 63) == 0) { sT[w] = mT; sC[w] = mC; }
    __syncthreads();
    if (threadIdx.x == 0) {
        mT = fmaxf(fmaxf(sT[0], sT[1]), fmaxf(sT[2], sT[3]));
        mC = fmaxf(fmaxf(sC[0], sC[1]), fmaxf(sC[2], sC[3]));
        ws_max[2 * blockIdx.x]     = mT;
        ws_max[2 * blockIdx.x + 1] = mC;
    }
}

__global__ __launch_bounds__(256) void kmain(const float* __restrict__ target,
                                             const int* __restrict__ mask,
                                             const float* __restrict__ centers,
                                             const float* __restrict__ ws_max,
                                             float* __restrict__ ws_min,
                                             float* __restrict__ ws_dir2) {
    __shared__ float s_c[NC];
    __shared__ float s_wmin[4 * NC];
    __shared__ float s_red[8];
    __shared__ float s_pad;
    const int tid = threadIdx.x;
    const int b   = blockIdx.y;
    const int blk = blockIdx.x;
    const int w   = tid >> 6;

    // ---- phase 1: reduce the 300 max-pairs -> pad_value; stage centers ----
    float mT = -INFINITY, mC = -INFINITY;
    for (int i = tid; i < K1_BLOCKS; i += TPB) {
        mT = fmaxf(mT, ws_max[2 * i]);
        mC = fmaxf(mC, ws_max[2 * i + 1]);
    }
    for (int o = 32; o > 0; o >>= 1) {
        mT = fmaxf(mT, __shfl_down(mT, o));
        mC = fmaxf(mC, __shfl_down(mC, o));
    }
    if ((tid & 63) == 0) { s_red[w] = mT; s_red[4 + w] = mC; }
    if (tid < NBINS) s_c[tid] = centers[b * NBINS + tid];
    __syncthreads();
    if (tid == 0) {
        float aT = fmaxf(fmaxf(s_red[0], s_red[1]), fmaxf(s_red[2], s_red[3]));
        float aC = fmaxf(fmaxf(s_red[4], s_red[5]), fmaxf(s_red[6], s_red[7]));
        float mx = fmaxf(aT, aC), mn = fminf(aT, aC);
        float pad = mx + (mx - mn) + 1.0f;   // EPS = 1.0
        s_pad = pad;
        s_c[NBINS] = pad;                    // padded 257th center
    }
    __syncthreads();
    const float pad = s_pad;

    // ---- phase 2: load this block's pixels into registers ----
    const int base = b * HW + blk * (TPB * P);
    float t[P], min2[P];
#pragma unroll
    for (int p = 0; p < P; ++p) {
        int i = base + p * TPB + tid;
        float v = target[i];
        t[p] = mask[i] ? v : pad;
        min2[p] = INFINITY;
    }

    // ---- phase 3: m-loop computes both directions from registers ----
    for (int m = 0; m < NC; ++m) {
        float c = s_c[m];
        float lmin = INFINITY;
#pragma unroll
        for (int p = 0; p < P; ++p) {
            float d = t[p] - c;
            float d2 = d * d;
            min2[p] = fminf(min2[p], d2);
            lmin = fminf(lmin, d2);
        }
        for (int o = 32; o > 0; o >>= 1)
            lmin = fminf(lmin, __shfl_down(lmin, o));
        if ((tid & 63) == 0) s_wmin[w * NC + m] = lmin;
    }

    // ---- dir2 per-thread sum ----
    float acc = 0.f;
#pragma unroll
    for (int p = 0; p < P; ++p) acc += min2[p];
    for (int o = 32; o > 0; o >>= 1) acc += __shfl_down(acc, o);
    if ((tid & 63) == 0) s_red[w] = acc;
    __syncthreads();

    // ---- write per-block partials ----
    const int outbase = (b * K2_BPB + blk) * NC;
    for (int m = tid; m < NC; m += TPB) {
        float gm = fminf(fminf(s_wmin[m], s_wmin[NC + m]),
                         fminf(s_wmin[2 * NC + m], s_wmin[3 * NC + m]));
        ws_min[outbase + m] = gm;
    }
    if (tid == 0)
        ws_dir2[b * K2_BPB + blk] = s_red[0] + s_red[1] + s_red[2] + s_red[3];
}

__global__ __launch_bounds__(1024) void kfinal(const float* __restrict__ ws_min,
                                               const float* __restrict__ ws_dir2,
                                               float* __restrict__ out) {
    const int tid = threadIdx.x;
    float acc = 0.f;
    // dir1: for each (b,m), min over the 50 block partials, then sum
    for (int idx = tid; idx < B * NC; idx += 1024) {
        int b = idx / NC, m = idx % NC;
        float mn = INFINITY;
        for (int k = 0; k < K2_BPB; ++k)
            mn = fminf(mn, ws_min[(b * K2_BPB + k) * NC + m]);
        acc += mn;
    }
    // dir2 partial sums
    for (int i = tid; i < B * K2_BPB; i += 1024) acc += ws_dir2[i];
    for (int o = 32; o > 0; o >>= 1) acc += __shfl_down(acc, o);
    __shared__ float s[16];
    if ((tid & 63) == 0) s[tid >> 6] = acc;
    __syncthreads();
    if (tid == 0) {
        float tot = 0.f;
        for (int i = 0; i < 16; ++i) tot += s[i];
        out[0] = tot * (1.0f / B);
    }
}

extern "C" void kernel_launch(void* const* d_in, const int* in_sizes, int n_in,
                              void* d_out, int out_size, void* d_ws, size_t ws_size,
                              hipStream_t stream) {
    const float* target  = (const float*)d_in[0];
    const float* centers = (const float*)d_in[1];
    const int*   mask    = (const int*)d_in[2];
    float* out = (float*)d_out;
    float* ws  = (float*)d_ws;

    float* ws_max  = ws + WS_MAX_OFF;
    float* ws_min  = ws + WS_MIN_OFF;
    float* ws_dir2 = ws + WS_DIR2_OFF;

    kmax<<<K1_BLOCKS, TPB, 0, stream>>>(target, mask, centers, ws_max);
    dim3 g2(K2_BPB, B);
    kmain<<<g2, TPB, 0, stream>>>(target, mask, centers, ws_max, ws_min, ws_dir2);
    kfinal<<<1, 1024, 0, stream>>>(ws_min, ws_dir2, out);
}

// Round 2
// 97.618 us; speedup vs baseline: 1.6916x; 1.6916x over previous
//
#include <hip/hip_runtime.h>
#include <math.h>

#define B 4
#define HW 76800       // 240*320
#define NBINS 256
#define NC 257         // bins + pad center
#define K1_BLOCKS 300
#define K2_BPB 150     // blocks per batch (150*256*2 == 76800 exactly)
#define P 2            // pixels per thread
#define TPB 256
#define PXB (TPB * P)  // 512 pixels per block

// ws layout (4-byte words):
//   [0, 600)      : K1 per-block {maxT, maxC} pairs
//   [600, 1628)   : dir1 per-(b,m) running min (uint-bits of float, atomicMin)
//   [1628, 1632)  : dir2 per-batch sums (float, atomicAdd)
#define WS_MAX_OFF  0
#define WS_DIR1_OFF 600
#define WS_DIR2_OFF (600 + B * NC)   // 1628

__global__ __launch_bounds__(256) void kmax(const float* __restrict__ target,
                                            const int* __restrict__ mask,
                                            const float* __restrict__ centers,
                                            float* __restrict__ ws_max) {
    int tid = blockIdx.x * 256 + threadIdx.x;
    const int stride = K1_BLOCKS * 256;   // 76800
    float mT = -INFINITY;
#pragma unroll
    for (int r = 0; r < 4; ++r) {         // 4*76800 = 307200 = B*HW exactly
        int i = tid + r * stride;
        float v = target[i];
        if (mask[i]) mT = fmaxf(mT, v);
    }
    float mC = -INFINITY;
    if (tid < B * NBINS) mC = centers[tid];
    for (int o = 32; o > 0; o >>= 1) {
        mT = fmaxf(mT, __shfl_down(mT, o));
        mC = fmaxf(mC, __shfl_down(mC, o));
    }
    __shared__ float sT[4], sC[4];
    int w = threadIdx.x >> 6;
    if ((threadIdx.x & 63) == 0) { sT[w] = mT; sC[w] = mC; }
    __syncthreads();
    if (threadIdx.x == 0) {
        mT = fmaxf(fmaxf(sT[0], sT[1]), fmaxf(sT[2], sT[3]));
        mC = fmaxf(fmaxf(sC[0], sC[1]), fmaxf(sC[2], sC[3]));
        ws_max[2 * blockIdx.x]     = mT;
        ws_max[2 * blockIdx.x + 1] = mC;
    }
}

__global__ __launch_bounds__(256) void kmain(const float* __restrict__ target,
                                             const int* __restrict__ mask,
                                             const float* __restrict__ centers,
                                             const float* __restrict__ ws_max,
                                             unsigned int* __restrict__ ws_dir1,
                                             float* __restrict__ ws_dir2) {
    __shared__ __align__(16) float s_c[NC + 3];   // +3 so float4 tail read is in-bounds
    __shared__ __align__(16) float s_t[PXB];
    __shared__ float s_red[8];
    __shared__ float s_pad;
    const int tid = threadIdx.x;
    const int b   = blockIdx.y;
    const int blk = blockIdx.x;
    const int w   = tid >> 6;

    // ---- phase 1: reduce the 300 max-pairs -> pad_value; stage centers ----
    float mT = -INFINITY, mC = -INFINITY;
    for (int i = tid; i < K1_BLOCKS; i += TPB) {
        mT = fmaxf(mT, ws_max[2 * i]);
        mC = fmaxf(mC, ws_max[2 * i + 1]);
    }
    for (int o = 32; o > 0; o >>= 1) {
        mT = fmaxf(mT, __shfl_down(mT, o));
        mC = fmaxf(mC, __shfl_down(mC, o));
    }
    if ((tid & 63) == 0) { s_red[w] = mT; s_red[4 + w] = mC; }
    if (tid < NBINS) s_c[tid] = centers[b * NBINS + tid];
    __syncthreads();
    if (tid == 0) {
        float aT = fmaxf(fmaxf(s_red[0], s_red[1]), fmaxf(s_red[2], s_red[3]));
        float aC = fmaxf(fmaxf(s_red[4], s_red[5]), fmaxf(s_red[6], s_red[7]));
        float mx = fmaxf(aT, aC), mn = fminf(aT, aC);
        float pad = mx + (mx - mn) + 1.0f;   // EPS = 1.0
        s_pad = pad;
        s_c[NBINS] = pad;                    // padded 257th center
        s_c[NBINS + 1] = pad;                // dead lanes for float4 tail
        s_c[NBINS + 2] = pad;
        s_c[NBINS + 3] = pad;
    }
    __syncthreads();
    const float pad = s_pad;

    // ---- phase 2: pixels -> registers + LDS stage ----
    const int base = b * HW + blk * PXB;
    float t[P], min2[P];
#pragma unroll
    for (int p = 0; p < P; ++p) {
        int i = base + p * TPB + tid;
        float v = target[i];
        t[p] = mask[i] ? v : pad;
        s_t[p * TPB + tid] = t[p];
        min2[p] = INFINITY;
    }
    __syncthreads();

    // ---- Loop A (dir2): per-pixel min over all 257 centers, no cross-lane ----
    const float4* s_c4 = (const float4*)s_c;
#pragma unroll 4
    for (int mq = 0; mq < 64; ++mq) {        // 64*4 = 256 real centers
        float4 c = s_c4[mq];
#pragma unroll
        for (int p = 0; p < P; ++p) {
            float d0 = t[p] - c.x, d1 = t[p] - c.y;
            float d2 = t[p] - c.z, d3 = t[p] - c.w;
            min2[p] = fminf(min2[p], fminf(fminf(d0 * d0, d1 * d1),
                                           fminf(d2 * d2, d3 * d3)));
        }
    }
    {   // pad center (index 256)
        float c = s_c[NBINS];
#pragma unroll
        for (int p = 0; p < P; ++p) {
            float d = t[p] - c;
            min2[p] = fminf(min2[p], d * d);
        }
    }

    // ---- Loop B (dir1): thread owns center tid (+256 for tid==0) ----
    const float4* s_t4 = (const float4*)s_t;
    for (int mi = tid; mi < NC; mi += TPB) {
        float c = s_c[mi];
        float cmin = INFINITY;
#pragma unroll 8
        for (int j = 0; j < PXB / 4; ++j) {
            float4 v = s_t4[j];
            float d0 = v.x - c, d1 = v.y - c, d2 = v.z - c, d3 = v.w - c;
            cmin = fminf(cmin, fminf(fminf(d0 * d0, d1 * d1),
                                     fminf(d2 * d2, d3 * d3)));
        }
        atomicMin(&ws_dir1[b * NC + mi], __float_as_uint(cmin));
    }

    // ---- dir2 per-block sum -> atomicAdd ----
    float acc = 0.f;
#pragma unroll
    for (int p = 0; p < P; ++p) acc += min2[p];
    for (int o = 32; o > 0; o >>= 1) acc += __shfl_down(acc, o);
    __syncthreads();                          // s_red reuse safe-guard
    if ((tid & 63) == 0) s_red[w] = acc;
    __syncthreads();
    if (tid == 0)
        atomicAdd(&ws_dir2[b], s_red[0] + s_red[1] + s_red[2] + s_red[3]);
}

__global__ __launch_bounds__(256) void kfinal(const unsigned int* __restrict__ ws_dir1,
                                              const float* __restrict__ ws_dir2,
                                              float* __restrict__ out) {
    const int tid = threadIdx.x;
    float acc = 0.f;
    for (int i = tid; i < B * NC; i += 256)
        acc += __uint_as_float(ws_dir1[i]);   // stored as monotone uint bits
    if (tid < B) acc += ws_dir2[tid];
    for (int o = 32; o > 0; o >>= 1) acc += __shfl_down(acc, o);
    __shared__ float s[4];
    if ((tid & 63) == 0) s[tid >> 6] = acc;
    __syncthreads();
    if (tid == 0)
        out[0] = (s[0] + s[1] + s[2] + s[3]) * (1.0f / B);
}

extern "C" void kernel_launch(void* const* d_in, const int* in_sizes, int n_in,
                              void* d_out, int out_size, void* d_ws, size_t ws_size,
                              hipStream_t stream) {
    const float* target  = (const float*)d_in[0];
    const float* centers = (const float*)d_in[1];
    const int*   mask    = (const int*)d_in[2];
    float* out = (float*)d_out;
    float* ws  = (float*)d_ws;

    float*        ws_max  = ws + WS_MAX_OFF;
    unsigned int* ws_dir1 = (unsigned int*)(ws + WS_DIR1_OFF);
    float*        ws_dir2 = ws + WS_DIR2_OFF;

    // init: dir1 mins -> 0x7F7F7F7F (3.39e38, > any real d^2); dir2 sums -> 0
    hipMemsetAsync(ws_dir1, 0x7F, B * NC * sizeof(unsigned int), stream);
    hipMemsetAsync(ws_dir2, 0x00, B * sizeof(float), stream);

    kmax<<<K1_BLOCKS, TPB, 0, stream>>>(target, mask, centers, ws_max);
    dim3 g2(K2_BPB, B);
    kmain<<<g2, TPB, 0, stream>>>(target, mask, centers, ws_max, ws_dir1, ws_dir2);
    kfinal<<<1, TPB, 0, stream>>>(ws_dir1, ws_dir2, out);
}